// Round 8
// baseline (2317.984 us; speedup 1.0000x reference)
//
#include <hip/hip_runtime.h>
#include <hip/hip_bf16.h>
#include <math.h>

typedef __hip_bfloat16 bf16;
typedef __bf16 bf16x8 __attribute__((ext_vector_type(8)));
typedef float f32x4 __attribute__((ext_vector_type(4)));

__device__ __forceinline__ f32x4 zero4() { f32x4 z; z[0]=0.f; z[1]=0.f; z[2]=0.f; z[3]=0.f; return z; }

__device__ __forceinline__ void gload_lds16(const void* g, void* l) {
  __builtin_amdgcn_global_load_lds(
      (const __attribute__((address_space(1))) void*)g,
      (__attribute__((address_space(3))) void*)l, 16, 0, 0);
}

__device__ __forceinline__ float gelu_f(float t) {
  return 0.5f*t*(1.0f+erff(t*0.70710678118654752f));
}

// 2D XCD supertile: XCD c owns a compact SW x (L/SW) rectangle of tiles.
// Requires SW | gridDim.x and (gx/SW)*(gy/H) == 8.
template<int SW>
__device__ __forceinline__ void xcd_tile(int& bx, int& by) {
  const int gx = gridDim.x;
  const int nwg = gx * gridDim.y;
  const int orig = blockIdx.y * gx + blockIdx.x;
  const int L = nwg >> 3;
  const int c = orig & 7, i = orig >> 3;
  const int gxW = gx / SW;
  const int H = L / SW;
  bx = (c % gxW) * SW + i % SW;
  by = (c / gxW) * H + i / SW;
}

// ---------------- GEMM v7: 256x256, BK=64, 8 waves, 4 phases, issue-all/wait-once ----------------
// C(MxN) = A(MxK,bf16) * B^T (B is NxK bf16). MODE 0..4 epilogues.
template<int MODE, int SW>
__global__ __launch_bounds__(512, 2) void k_gemm2(
    const bf16* __restrict__ A, const bf16* __restrict__ B,
    int M, int N, int K,
    float* __restrict__ outf, bf16* __restrict__ outb,
    const float* __restrict__ bias)
{
  __shared__ __align__(16) char lds[2][65536];
  const int t = threadIdx.x;
  const int w = t>>6, l = t&63;
  const int wr = w>>2, wc = w&3;
  const int lr = l&15, l4 = l>>4, l7 = l&7;

  int bx, by; xcd_tile<SW>(bx, by);
  const int m0 = by*256, n0 = bx*256;

  const int NT = K >> 6;
  const size_t rs = (size_t)K*2;
  const char* gA = (const char*)A + (size_t)m0*rs;
  const char* gB = (const char*)B + (size_t)n0*rs;

  auto stageU = [&](char* dstbase, const char* gbase, int T, int rowbase){
    const size_t kb = (size_t)T*128;
    #pragma unroll
    for (int i=0;i<2;i++){
      const int row = rowbase + i*64 + (t>>3);
      gload_lds16(gbase + (size_t)row*rs + kb + (size_t)(((t&7) ^ (row&7))<<4),
                  dstbase + rowbase*128 + i*8192 + t*16);
    }
  };

  f32x4 acc[2][2][4][2];
  #pragma unroll
  for (int a=0;a<2;a++)
    #pragma unroll
    for (int b=0;b<2;b++)
      #pragma unroll
      for (int c=0;c<4;c++)
        #pragma unroll
        for (int d=0;d<2;d++) acc[a][b][c][d] = zero4();

  bf16x8 aCur[4][2], bCur[2][2];
  auto readA = [&](const char* Ab, int mhalf){
    #pragma unroll
    for (int mi=0;mi<4;mi++){
      const int ar = mhalf*128 + wr*64 + mi*16 + lr;
      #pragma unroll
      for (int ks=0;ks<2;ks++)
        aCur[mi][ks] = *reinterpret_cast<const bf16x8*>(Ab + ar*128 + (((ks*4+l4) ^ l7)<<4));
    }
  };
  auto readB = [&](const char* Bb, int nhalf){
    #pragma unroll
    for (int ni=0;ni<2;ni++){
      const int br = nhalf*128 + wc*32 + ni*16 + lr;
      #pragma unroll
      for (int ks=0;ks<2;ks++)
        bCur[ni][ks] = *reinterpret_cast<const bf16x8*>(Bb + br*128 + (((ks*4+l4) ^ l7)<<4));
    }
  };

  #define QMFMA(MH,NH)                                                              \
    __builtin_amdgcn_s_setprio(1);                                                  \
    _Pragma("unroll")                                                               \
    for (int mi=0;mi<4;mi++)                                                        \
      _Pragma("unroll")                                                             \
      for (int ni=0;ni<2;ni++)                                                      \
        _Pragma("unroll")                                                           \
        for (int ks=0;ks<2;ks++)                                                    \
          acc[MH][NH][mi][ni] = __builtin_amdgcn_mfma_f32_16x16x32_bf16(            \
              aCur[mi][ks], bCur[ni][ks], acc[MH][NH][mi][ni], 0,0,0);              \
    __builtin_amdgcn_s_setprio(0);

  // prologue: stage tile 0 fully, drain, publish
  stageU(&lds[0][0],        gA, 0, 0);
  stageU(&lds[0][0],        gA, 0, 128);
  stageU(&lds[0][0]+32768,  gB, 0, 0);
  stageU(&lds[0][0]+32768,  gB, 0, 128);
  asm volatile("s_waitcnt vmcnt(0)" ::: "memory");
  __builtin_amdgcn_s_barrier();

  for (int T=0; T<NT; ++T) {
    const int p = T & 1;
    char* Ab = &lds[p][0];
    char* Bb = Ab + 32768;
    char* An = &lds[p^1][0];
    char* Bn = An + 32768;
    const bool more = (T+1 < NT);

    // ph0: issue ALL of T+1 (WAR-safe: nxt's last reader crossed ph3 barrier of T-1)
    readA(Ab,0); readB(Bb,0);
    if (more) {
      stageU(An, gA, T+1, 0);
      stageU(An, gA, T+1, 128);
      stageU(Bn, gB, T+1, 0);
      stageU(Bn, gB, T+1, 128);
    }
    asm volatile("" ::: "memory");
    __builtin_amdgcn_s_barrier();
    QMFMA(0,0);

    // ph1
    readB(Bb,1);
    asm volatile("" ::: "memory");
    __builtin_amdgcn_s_barrier();
    QMFMA(0,1);

    // ph2
    readA(Ab,1);
    asm volatile("" ::: "memory");
    __builtin_amdgcn_s_barrier();
    QMFMA(1,1);

    // ph3: single drain for T+1's 8 loads (~3 phases of slack)
    readB(Bb,0);
    asm volatile("s_waitcnt vmcnt(0)" ::: "memory");
    __builtin_amdgcn_s_barrier();
    QMFMA(1,0);
  }
  #undef QMFMA

  const int rbase = m0 + wr*64 + l4*4;
  const int cbase = n0 + wc*32 + lr;
  #pragma unroll
  for (int mh=0;mh<2;mh++)
    #pragma unroll
    for (int nh=0;nh<2;nh++)
      #pragma unroll
      for (int mi=0;mi<4;mi++)
        #pragma unroll
        for (int ni=0;ni<2;ni++) {
          const int col = cbase + nh*128 + ni*16;
          #pragma unroll
          for (int q=0;q<4;q++) {
            const int row = rbase + mh*128 + mi*16 + q;
            const size_t idx = (size_t)row*N + col;
            float v = acc[mh][nh][mi][ni][q];
            if (MODE==0)      outf[idx] = v + bias[col];
            else if (MODE==1) outb[idx] = __float2bfloat16(v);
            else if (MODE==2) outf[idx] += v;
            else if (MODE==3) outb[idx] = __float2bfloat16(gelu_f(v + bias[col]));
            else if (MODE==4) outf[idx] += v + bias[col];
          }
        }
}

// ---------------- GEMM v7b: BM=128 x BN=256, BK=64, 8 waves, 4 phases, issue-all/wait-once ------
template<int MODE, int SW>
__global__ __launch_bounds__(512, 2) void k_gemm3(
    const bf16* __restrict__ A, const bf16* __restrict__ B,
    int M, int N, int K,
    float* __restrict__ outf, bf16* __restrict__ outb,
    const float* __restrict__ bias)
{
  // buf: A 128x64 (16KB) + B 256x64 (32KB) = 48KB x2
  __shared__ __align__(16) char lds[2][49152];
  const int t = threadIdx.x;
  const int w = t>>6, l = t&63;
  const int wr = w>>2, wc = w&3;
  const int lr = l&15, l4 = l>>4, l7 = l&7;

  int bx, by; xcd_tile<SW>(bx, by);
  const int m0 = by*128, n0 = bx*256;

  const int NT = K >> 6;
  const size_t rs = (size_t)K*2;
  const char* gA = (const char*)A + (size_t)m0*rs;
  const char* gB = (const char*)B + (size_t)n0*rs;

  auto stgA = [&](char* dst, int T, int j){
    const int row = j*64 + (t>>3);
    gload_lds16(gA + (size_t)row*rs + (size_t)T*128 + (size_t)(((t&7) ^ (row&7))<<4),
                dst + j*8192 + t*16);
  };
  auto stgB = [&](char* dst, int T, int j){
    const int row = j*64 + (t>>3);
    gload_lds16(gB + (size_t)row*rs + (size_t)T*128 + (size_t)(((t&7) ^ (row&7))<<4),
                dst + 16384 + j*8192 + t*16);
  };

  f32x4 acc[4][4];
  #pragma unroll
  for (int i=0;i<4;i++)
    #pragma unroll
    for (int j=0;j<4;j++) acc[i][j] = zero4();

  bf16x8 aCur[4], bCur[2];
  auto readA = [&](const char* base, int ks){
    #pragma unroll
    for (int mi=0;mi<4;mi++){
      const int ar = wr*64 + mi*16 + lr;
      aCur[mi] = *reinterpret_cast<const bf16x8*>(base + ar*128 + (((ks*4+l4) ^ l7)<<4));
    }
  };
  auto readB = [&](const char* base, int nh, int ks){
    #pragma unroll
    for (int nn=0;nn<2;nn++){
      const int br = (nh*2+nn)*64 + wc*16 + lr;
      bCur[nn] = *reinterpret_cast<const bf16x8*>(base + 16384 + br*128 + (((ks*4+l4) ^ l7)<<4));
    }
  };

  #define PMFMA(NB)                                                                 \
    __builtin_amdgcn_s_setprio(1);                                                  \
    _Pragma("unroll")                                                               \
    for (int mi=0;mi<4;mi++)                                                        \
      _Pragma("unroll")                                                             \
      for (int nn=0;nn<2;nn++)                                                      \
        acc[mi][NB+nn] = __builtin_amdgcn_mfma_f32_16x16x32_bf16(                   \
            aCur[mi], bCur[nn], acc[mi][NB+nn], 0,0,0);                             \
    __builtin_amdgcn_s_setprio(0);

  // prologue: all 6 units of tile 0, drain, publish
  stgA(&lds[0][0], 0, 0); stgA(&lds[0][0], 0, 1);
  stgB(&lds[0][0], 0, 0); stgB(&lds[0][0], 0, 1);
  stgB(&lds[0][0], 0, 2); stgB(&lds[0][0], 0, 3);
  asm volatile("s_waitcnt vmcnt(0)" ::: "memory");
  __builtin_amdgcn_s_barrier();

  for (int T=0; T<NT; ++T) {
    char* cur = &lds[T&1][0];
    char* nxt = &lds[(T&1)^1][0];
    const bool more = (T+1 < NT);

    // ph0: issue ALL of T+1
    readA(cur,0); readB(cur,0,0);
    if (more) {
      stgA(nxt,T+1,0); stgA(nxt,T+1,1);
      stgB(nxt,T+1,0); stgB(nxt,T+1,1);
      stgB(nxt,T+1,2); stgB(nxt,T+1,3);
    }
    asm volatile("" ::: "memory");
    __builtin_amdgcn_s_barrier();
    PMFMA(0);

    // ph1
    readB(cur,1,0);
    asm volatile("" ::: "memory");
    __builtin_amdgcn_s_barrier();
    PMFMA(2);

    // ph2
    readA(cur,1); readB(cur,1,1);
    asm volatile("" ::: "memory");
    __builtin_amdgcn_s_barrier();
    PMFMA(2);

    // ph3: single drain for T+1's 6 loads
    readB(cur,0,1);
    asm volatile("s_waitcnt vmcnt(0)" ::: "memory");
    __builtin_amdgcn_s_barrier();
    PMFMA(0);
  }
  #undef PMFMA

  const int rbase = m0 + wr*64 + l4*4;
  const int cb0 = n0 + wc*16 + lr;
  #pragma unroll
  for (int mi=0;mi<4;mi++)
    #pragma unroll
    for (int ni=0;ni<4;ni++) {
      const int col = cb0 + ni*64;
      #pragma unroll
      for (int q=0;q<4;q++) {
        const int row = rbase + mi*16 + q;
        const size_t idx = (size_t)row*N + col;
        float v = acc[mi][ni][q];
        if (MODE==0)      outf[idx] = v + bias[col];
        else if (MODE==1) outb[idx] = __float2bfloat16(v);
        else if (MODE==2) outf[idx] += v;
        else if (MODE==3) outb[idx] = __float2bfloat16(gelu_f(v + bias[col]));
        else if (MODE==4) outf[idx] += v + bias[col];
      }
    }
}

// ---------------- transpose: 64x64 tiles, float4 reads, ushort4 writes ----------------
__global__ __launch_bounds__(256) void k_tr64(const float* __restrict__ in, bf16* __restrict__ out,
                                              int K, int N)
{
  __shared__ float tile[64][65];
  const int n0 = blockIdx.x*64, k0 = blockIdx.y*64;
  const int t = threadIdx.x;
  const int tr = t>>4;
  const int tc = (t&15)*4;
  #pragma unroll
  for (int i=0;i<4;i++) {
    const int k = tr + i*16;
    float4 v = *reinterpret_cast<const float4*>(&in[(size_t)(k0+k)*N + n0 + tc]);
    tile[k][tc+0]=v.x; tile[k][tc+1]=v.y; tile[k][tc+2]=v.z; tile[k][tc+3]=v.w;
  }
  __syncthreads();
  #pragma unroll
  for (int i=0;i<4;i++) {
    const int n = tr + i*16;
    bf16 r[4];
    #pragma unroll
    for (int c=0;c<4;c++) r[c] = __float2bfloat16(tile[tc+c][n]);
    *reinterpret_cast<ushort4*>(&out[(size_t)(n0+n)*K + k0 + tc]) = *reinterpret_cast<const ushort4*>(r);
  }
}

__global__ void k_cvt(const float* __restrict__ in, bf16* __restrict__ out, int n4) {
  int i = blockIdx.x*256 + threadIdx.x;
  if (i < n4) {
    float4 v = reinterpret_cast<const float4*>(in)[i];
    out[i*4+0]=__float2bfloat16(v.x); out[i*4+1]=__float2bfloat16(v.y);
    out[i*4+2]=__float2bfloat16(v.z); out[i*4+3]=__float2bfloat16(v.w);
  }
}

__global__ void k_cossin(float* __restrict__ c, float* __restrict__ s) {
  int idx = blockIdx.x*256 + threadIdx.x;   // 1024*64
  int j = idx & 63, pos = idx >> 6;
  float inv = powf(10000.f, -(float)(2*j)/128.f);
  float a = (float)pos * inv;
  c[idx] = cosf(a); s[idx] = sinf(a);
}

// rope: in (4096 x instride), head block at h*128; out compact (4096 x 2048)
__global__ void k_rope(const bf16* __restrict__ in, int instride, bf16* __restrict__ out,
                       const float* __restrict__ cosc, const float* __restrict__ sinc) {
  int idx = blockIdx.x*256 + threadIdx.x;   // 4096*16*64
  int j = idx & 63, h = (idx>>6) & 15, row = idx >> 10;
  int s = row & 1023;
  const bf16* rp = in + (size_t)row*instride + h*128;
  float x1 = __bfloat162float(rp[2*j]), x2 = __bfloat162float(rp[2*j+1]);
  float c = cosc[s*64+j], sn = sinc[s*64+j];
  bf16* op = out + (size_t)row*2048 + h*128;
  op[j]    = __float2bfloat16(x1*c - x2*sn);
  op[j+64] = __float2bfloat16(x1*sn + x2*c);
}

// V (row=b*1024+s of [4096 x instride], col=h*128+d) -> Vt[(bh*128+d)*1024 + s]
__global__ __launch_bounds__(256) void k_vtrans(const bf16* __restrict__ vlin, int instride,
                                                bf16* __restrict__ vt) {
  __shared__ bf16 tile[32][33];
  const int bh = blockIdx.x, s0 = blockIdx.y*32, d0 = blockIdx.z*32;
  const int b = bh>>4, h = bh&15;
  const int tx = threadIdx.x & 31, ty = threadIdx.x >> 5;
  #pragma unroll
  for (int i=ty;i<32;i+=8)
    tile[i][tx] = vlin[((size_t)(b*1024 + s0+i))*instride + h*128 + d0 + tx];
  __syncthreads();
  #pragma unroll
  for (int i=ty;i<32;i+=8)
    vt[((size_t)(bh*128 + d0+i))*1024 + s0 + tx] = tile[tx][i];
}

// ---------------- flash attention: LDS-staged K/V, double-buffered, XOR-swizzled ----------------
__global__ __launch_bounds__(256) void k_attn(const bf16* __restrict__ Q, const bf16* __restrict__ Kr,
                                              const bf16* __restrict__ Vt, bf16* __restrict__ O)
{
  __shared__ __align__(16) bf16 Kl[2][64*128];
  __shared__ __align__(16) bf16 Vl[2][128*64];
  __shared__ __align__(16) bf16 plds[4][16*64];
  const int t = threadIdx.x, w = t>>6, l = t&63;
  const int bh = blockIdx.x, b = bh>>4, h = bh&15;
  const int q0 = blockIdx.y*64 + w*16;
  const int l4 = l>>4, lc = l&15;

  bf16x8 qf[4];
  const bf16* qbase = Q + ((size_t)(b*1024 + q0 + lc))*2048 + h*128 + l4*8;
  #pragma unroll
  for (int kk=0;kk<4;kk++) qf[kk] = *reinterpret_cast<const bf16x8*>(qbase + kk*32);

  const char* Kg = (const char*)(Kr + ((size_t)(b*1024))*2048 + h*128);
  const char* Vg = (const char*)(Vt + ((size_t)(bh*128))*1024);

  auto stageK = [&](int buf, int kv0) {
    #pragma unroll
    for (int i=0;i<4;i++) {
      const int X = (i*256 + t)*16;
      const int row = X >> 8, colb = X & 255;
      gload_lds16(Kg + (size_t)(kv0+row)*4096 + (colb ^ ((row&7)<<4)), (char*)&Kl[buf][0] + X);
    }
  };
  auto stageV = [&](int buf, int kv0) {
    #pragma unroll
    for (int i=0;i<4;i++) {
      const int X = (i*256 + t)*16;
      const int row = X >> 7, colb = X & 127;
      gload_lds16(Vg + (size_t)row*2048 + kv0*2 + (colb ^ ((row&7)<<4)), (char*)&Vl[buf][0] + X);
    }
  };

  f32x4 oacc[8];
  #pragma unroll
  for (int n=0;n<8;n++) oacc[n]=zero4();
  float mrow[4], lrow[4];
  #pragma unroll
  for (int j=0;j<4;j++){ mrow[j]=-1e30f; lrow[j]=0.f; }
  const float scale = 0.08838834764831845f;

  stageK(0,0); stageV(0,0);
  __syncthreads();
  int cur = 0;

  for (int it=0; it<16; ++it) {
    const int kv0 = it*64;
    if (it < 15) { stageK(cur^1, kv0+64); stageV(cur^1, kv0+64); }

    f32x4 sc[4];
    #pragma unroll
    for (int c=0;c<4;c++) sc[c]=zero4();
    __builtin_amdgcn_s_setprio(1);
    #pragma unroll
    for (int c=0;c<4;c++) {
      const int krow = c*16+lc;
      const char* kp = (const char*)&Kl[cur][0] + krow*256;
      #pragma unroll
      for (int kk=0;kk<4;kk++) {
        bf16x8 kf = *reinterpret_cast<const bf16x8*>(kp + ((kk*64 + l4*16) ^ ((krow&7)<<4)));
        sc[c] = __builtin_amdgcn_mfma_f32_16x16x32_bf16(qf[kk], kf, sc[c], 0,0,0);
      }
    }
    __builtin_amdgcn_s_setprio(0);

    float alpha[4];
    #pragma unroll
    for (int j=0;j<4;j++) {
      float v0=sc[0][j]*scale, v1=sc[1][j]*scale, v2=sc[2][j]*scale, v3=sc[3][j]*scale;
      float mx = fmaxf(fmaxf(v0,v1),fmaxf(v2,v3));
      #pragma unroll
      for (int d=1;d<16;d<<=1) mx = fmaxf(mx, __shfl_xor(mx,d));
      float mn = fmaxf(mrow[j], mx);
      alpha[j] = __expf(mrow[j]-mn);
      mrow[j] = mn;
      float p0=__expf(v0-mn), p1=__expf(v1-mn), p2=__expf(v2-mn), p3=__expf(v3-mn);
      sc[0][j]=p0; sc[1][j]=p1; sc[2][j]=p2; sc[3][j]=p3;
      float ps = (p0+p1)+(p2+p3);
      #pragma unroll
      for (int d=1;d<16;d<<=1) ps += __shfl_xor(ps,d);
      lrow[j] = lrow[j]*alpha[j] + ps;
    }
    #pragma unroll
    for (int n=0;n<8;n++)
      #pragma unroll
      for (int j=0;j<4;j++) oacc[n][j]*=alpha[j];

    char* pw = (char*)&plds[w][0];
    #pragma unroll
    for (int c=0;c<4;c++)
      #pragma unroll
      for (int j=0;j<4;j++) {
        const int qrow = l4*4+j;
        *reinterpret_cast<bf16*>(pw + qrow*128 + ((c*32 + lc*2) ^ ((qrow&7)<<4))) =
            __float2bfloat16(sc[c][j]);
      }
    bf16x8 pf[2];
    #pragma unroll
    for (int ks=0;ks<2;ks++)
      pf[ks] = *reinterpret_cast<const bf16x8*>(pw + lc*128 + ((ks*64 + l4*16) ^ ((lc&7)<<4)));

    __builtin_amdgcn_s_setprio(1);
    #pragma unroll
    for (int n=0;n<8;n++) {
      const int drow = n*16+lc;
      const char* vp = (const char*)&Vl[cur][0] + drow*128;
      #pragma unroll
      for (int ks=0;ks<2;ks++) {
        bf16x8 vf = *reinterpret_cast<const bf16x8*>(vp + ((ks*64 + l4*16) ^ ((drow&7)<<4)));
        oacc[n] = __builtin_amdgcn_mfma_f32_16x16x32_bf16(pf[ks], vf, oacc[n], 0,0,0);
      }
    }
    __builtin_amdgcn_s_setprio(0);

    __syncthreads();
    cur ^= 1;
  }

  #pragma unroll
  for (int n=0;n<8;n++)
    #pragma unroll
    for (int j=0;j<4;j++) {
      float v = oacc[n][j]/lrow[j];
      O[((size_t)(b*1024 + q0 + l4*4 + j))*2048 + h*128 + n*16 + lc] = __float2bfloat16(v);
    }
}

// ---------------- LayerNorm over 2048 cols; optional per-(b,col) add; fp32+bf16 out ----------------
__global__ __launch_bounds__(256) void k_ln(const float* __restrict__ in, const float* __restrict__ addv,
                                            float* __restrict__ outf, bf16* __restrict__ outb,
                                            const float* __restrict__ g, const float* __restrict__ bta)
{
  const int row = blockIdx.x;
  const int b = row >> 10;
  const float* src = in + (size_t)row*2048;
  float vals[8];
  float s = 0.f;
  #pragma unroll
  for (int i=0;i<8;i++) {
    int c = threadIdx.x + i*256;
    float v = src[c];
    if (addv) v += addv[b*2048 + c];
    vals[i]=v; s+=v;
  }
  __shared__ float red[256];
  red[threadIdx.x]=s; __syncthreads();
  for (int o=128;o>0;o>>=1){ if(threadIdx.x<o) red[threadIdx.x]+=red[threadIdx.x+o]; __syncthreads(); }
  float mean = red[0] * (1.f/2048.f);
  __syncthreads();
  float vs=0.f;
  #pragma unroll
  for (int i=0;i<8;i++){ float d=vals[i]-mean; vs+=d*d; }
  red[threadIdx.x]=vs; __syncthreads();
  for (int o=128;o>0;o>>=1){ if(threadIdx.x<o) red[threadIdx.x]+=red[threadIdx.x+o]; __syncthreads(); }
  float inv = rsqrtf(red[0]*(1.f/2048.f) + 1e-5f);
  #pragma unroll
  for (int i=0;i<8;i++){
    int c = threadIdx.x + i*256;
    float r = (vals[i]-mean)*inv*g[c] + bta[c];
    if (outf) outf[(size_t)row*2048+c]=r;
    if (outb) outb[(size_t)row*2048+c]=__float2bfloat16(r);
  }
}

// mean over s: in (4x1024 x 2048 fp32) -> out (4 x 2048)
__global__ __launch_bounds__(256) void k_pool(const float* __restrict__ in, float* __restrict__ out) {
  const int b = blockIdx.y;
  const int c0 = blockIdx.x*64;
  const int col = threadIdx.x & 63, rg = threadIdx.x >> 6;
  float s=0.f;
  for (int i=rg*256; i<rg*256+256; ++i)
    s += in[((size_t)(b*1024) + i)*2048 + c0 + col];
  __shared__ float red[4][64];
  red[rg][col] = s; __syncthreads();
  if (threadIdx.x < 64) {
    float v = red[0][col]+red[1][col]+red[2][col]+red[3][col];
    out[b*2048 + c0 + col] = v * (1.f/1024.f);
  }
}

__global__ __launch_bounds__(256) void k_gate(const float* __restrict__ xp, const float* __restrict__ wg,
                                              const float* __restrict__ bg, const float* __restrict__ tau,
                                              float* __restrict__ hf)
{
  const int n = blockIdx.x*256 + threadIdx.x;
  const int b = blockIdx.y;
  float s = bg[n];
  const float* xr = xp + b*2048;
  for (int k=0;k<2048;k++) s += xr[k]*wg[(size_t)k*2048 + n];
  float gate = 1.f/(1.f+__expf(-s));
  float tf = 0.1f + 9.9f/(1.f+__expf(-tau[n]));
  hf[b*2048+n] = 0.1f*gate*xr[n]/tf;
}

// ---------------- head ----------------
__global__ void k_qm(const float* __restrict__ pooled, const float* __restrict__ w_mp,
                     const float* __restrict__ b_mp, float* __restrict__ qm) {
  int n = blockIdx.x*256 + threadIdx.x;  // 512
  int b = blockIdx.y;
  float s = b_mp[n];
  for (int k=0;k<2048;k++) s += pooled[b*2048+k]*w_mp[(size_t)k*512+n];
  qm[b*512+n]=s;
}

__global__ void k_mscore(const float* __restrict__ qm, const float* __restrict__ bank,
                         float* __restrict__ mattn) {
  int n = blockIdx.x*256 + threadIdx.x;
  if (n >= 10000) return;
  const float sc = 0.04419417382415922f;  // 1/sqrt(512)
  #pragma unroll
  for (int b=0;b<4;b++){
    float s=0.f;
    for (int k=0;k<512;k++) s += qm[b*512+k]*bank[(size_t)n*512+k];
    mattn[b*10000+n] = s*sc;
  }
}

__global__ __launch_bounds__(256) void k_msoftmax(float* __restrict__ mattn) {
  int b = blockIdx.x;
  __shared__ float red[256];
  float mx=-1e30f;
  for (int i=threadIdx.x;i<10000;i+=256) mx=fmaxf(mx, mattn[b*10000+i]);
  red[threadIdx.x]=mx; __syncthreads();
  for (int o=128;o>0;o>>=1){ if(threadIdx.x<o) red[threadIdx.x]=fmaxf(red[threadIdx.x],red[threadIdx.x+o]); __syncthreads(); }
  mx=red[0]; __syncthreads();
  float sm=0.f;
  for (int i=threadIdx.x;i<10000;i+=256){ float e=__expf(mattn[b*10000+i]-mx); mattn[b*10000+i]=e; sm+=e; }
  red[threadIdx.x]=sm; __syncthreads();
  for (int o=128;o>0;o>>=1){ if(threadIdx.x<o) red[threadIdx.x]+=red[threadIdx.x+o]; __syncthreads(); }
  float inv = 1.f/red[0];
  for (int i=threadIdx.x;i<10000;i+=256) mattn[b*10000+i]*=inv;
}

__global__ void k_memmid(const float* __restrict__ mattn, const float* __restrict__ bank,
                         float* __restrict__ part) {
  int d = blockIdx.x*256 + threadIdx.x;  // 512
  int b = blockIdx.y, ch = blockIdx.z;   // 16 chunks x 625
  float s=0.f;
  for (int n=ch*625;n<(ch+1)*625;n++) s += mattn[b*10000+n]*bank[(size_t)n*512+d];
  part[(size_t)ch*2048 + b*512 + d]=s;
}

__global__ void k_midsum(const float* __restrict__ part, float* __restrict__ mid) {
  int i = blockIdx.x*256 + threadIdx.x;  // 2048
  float s=0.f;
  #pragma unroll
  for (int ch=0;ch<16;ch++) s += part[(size_t)ch*2048 + i];
  mid[i]=s;
}

__global__ void k_feat(const float* __restrict__ mid, const float* __restrict__ w_mr,
                       const float* __restrict__ b_mr, const float* __restrict__ pooled,
                       float* __restrict__ feat) {
  int n = blockIdx.x*256 + threadIdx.x;  // 2048
  int b = blockIdx.y;
  float s = b_mr[n];
  for (int d=0;d<512;d++) s += mid[b*512+d]*w_mr[(size_t)d*2048+n];
  feat[b*2048+n] = pooled[b*2048+n] + s;
}

__global__ void k_mlp1(const float* __restrict__ feat, const float* __restrict__ w,
                       const float* __restrict__ bias, float* __restrict__ out) {
  int n = blockIdx.x*256 + threadIdx.x;  // 1024
  int b = blockIdx.y;
  float s = bias[n];
  for (int k=0;k<2048;k++) s += feat[b*2048+k]*w[(size_t)k*1024+n];
  out[b*1024+n] = gelu_f(s);
}

__global__ void k_out(const float* __restrict__ a1, const float* __restrict__ w_a2, const float* __restrict__ b_a2,
                      const float* __restrict__ v1, const float* __restrict__ w_v2, const float* __restrict__ b_v2,
                      float* __restrict__ out) {
  int idx = blockIdx.x*256 + threadIdx.x;  // 1024
  if (idx < 1024) {
    int b = idx>>8, n = idx&255;
    float s = b_a2[n];
    for (int k=0;k<1024;k++) s += a1[b*1024+k]*w_a2[(size_t)k*256+n];
    out[b*256+n]=s;
  }
  if (idx < 4) {
    float s = b_v2[0];
    for (int k=0;k<1024;k++) s += v1[idx*1024+k]*w_v2[k];
    out[1024+idx]=s;
  }
}

extern "C" void kernel_launch(void* const* d_in, const int* in_sizes, int n_in,
                              void* d_out, int out_size, void* d_ws, size_t ws_size,
                              hipStream_t stream)
{
  (void)in_sizes; (void)n_in; (void)out_size;
  const float* x     = (const float*)d_in[0];
  const float* w_in  = (const float*)d_in[1];
  const float* b_in  = (const float*)d_in[2];
  const float* g_in  = (const float*)d_in[3];
  const float* be_in = (const float*)d_in[4];
  const float* wq    = (const float*)d_in[5];
  const float* wk    = (const float*)d_in[6];
  const float* wv    = (const float*)d_in[7];
  const float* wo    = (const float*)d_in[8];
  const float* g1    = (const float*)d_in[11];
  const float* be1   = (const float*)d_in[12];
  const float* g2    = (const float*)d_in[13];
  const float* be2   = (const float*)d_in[14];
  const float* wff1  = (const float*)d_in[15];
  const float* bff1  = (const float*)d_in[16];
  const float* wff2  = (const float*)d_in[17];
  const float* bff2  = (const float*)d_in[18];
  const float* wgate = (const float*)d_in[19];
  const float* bgate = (const float*)d_in[20];
  const float* tauff = (const float*)d_in[21];
  const float* bank  = (const float*)d_in[22];
  const float* w_mp  = (const float*)d_in[23];
  const float* b_mp  = (const float*)d_in[24];
  const float* w_mr  = (const float*)d_in[25];
  const float* b_mr  = (const float*)d_in[26];
  const float* w_a1  = (const float*)d_in[27];
  const float* b_a1  = (const float*)d_in[28];
  const float* w_a2  = (const float*)d_in[29];
  const float* b_a2  = (const float*)d_in[30];
  const float* w_v1  = (const float*)d_in[31];
  const float* b_v1  = (const float*)d_in[32];
  const float* w_v2  = (const float*)d_in[33];
  const float* b_v2  = (const float*)d_in[34];
  float* out = (float*)d_out;

  char* ws = (char*)d_ws;
  size_t o = 0;
  auto alloc = [&](size_t bytes)->char* { char* p = ws + o; o += (bytes + 255) & ~(size_t)255; return p; };
  bf16*  WINT   = (bf16*) alloc(2048ull*1024*2);
  bf16*  WT     = (bf16*) alloc(33554432ull);
  float* XF     = (float*)alloc(33554432ull);
  bf16*  XBF    = (bf16*) alloc(16777216ull);
  float* COS    = (float*)alloc(262144);
  float* SIN    = (float*)alloc(262144);
  float* XP     = (float*)alloc(32768);
  float* HF     = (float*)alloc(32768);
  float* POOLED = (float*)alloc(32768);
  float* QM     = (float*)alloc(8192);
  float* MATTN  = (float*)alloc(160000);
  float* MPART  = (float*)alloc(131072);
  float* MIDS   = (float*)alloc(8192);
  float* FEAT   = (float*)alloc(32768);
  float* A1     = (float*)alloc(16384);
  float* V1     = (float*)alloc(16384);
  bf16*  BUF    = (bf16*) alloc(5ull*16777216);
  if (o > ws_size) return;

  const size_t EB = 8388608;
  bf16* QKV = BUF + 0*EB;          // fused q|k|v output, 4096 x 6144, spans BUF0..BUF2
  bf16* QR  = BUF + 3*EB;
  bf16* KR  = BUF + 4*EB;
  bf16* VT  = (bf16*)WT;           // 8.39M elems into dead WTq/WTk (after QKV gemm)
  bf16* AO  = BUF + 0*EB;          // reuses QKV after ropes/vtrans
  bf16* YBF = BUF + 4*EB;          // reuses KR after attention
  bf16* MID = BUF + 0*EB;          // 67MB spans BUF0..BUF3
  float* TF = (float*)(BUF + 1*EB);
  bf16* XINB = BUF + 0*EB;

  bf16* WTq = WT;            bf16* WTk = WT + 4194304;
  bf16* WTv = WT + 8388608;  bf16* WTo = WT + 12582912;

  // ---- prologue ----
  k_cossin<<<256, 256, 0, stream>>>(COS, SIN);
  k_cvt<<<4096, 256, 0, stream>>>(x, XINB, 1048576);
  k_tr64<<<dim3(32,16), 256, 0, stream>>>(w_in, WINT, 1024, 2048);
  k_gemm3<0,4><<<dim3(8,32), 512, 0, stream>>>(XINB, WINT, 4096, 2048, 1024, TF, (bf16*)nullptr, b_in);
  k_ln<<<4096, 256, 0, stream>>>(TF, (const float*)nullptr, XF, XBF, g_in, be_in);

  for (int i=0;i<2;i++) {
    const size_t ws2 = (size_t)i*2048*2048;
    k_tr64<<<dim3(32,32), 256, 0, stream>>>(wq + ws2, WTq, 2048, 2048);
    k_tr64<<<dim3(32,32), 256, 0, stream>>>(wk + ws2, WTk, 2048, 2048);
    k_tr64<<<dim3(32,32), 256, 0, stream>>>(wv + ws2, WTv, 2048, 2048);
    k_tr64<<<dim3(32,32), 256, 0, stream>>>(wo + ws2, WTo, 2048, 2048);
    // fused QKV projection: N=6144 (grid 24x16, XCD chunk 6x8)
    k_gemm2<1,6><<<dim3(24,16), 512, 0, stream>>>(XBF, WTq, 4096, 6144, 2048, (float*)nullptr, QKV, (const float*)nullptr);
    // RoPE + V transpose (VT lives in dead WTq/WTk region)
    k_rope<<<16384, 256, 0, stream>>>(QKV,        6144, QR, COS, SIN);
    k_rope<<<16384, 256, 0, stream>>>(QKV + 2048, 6144, KR, COS, SIN);
    k_vtrans<<<dim3(64,32,4), 256, 0, stream>>>(QKV + 4096, 6144, VT);
    // attention
    k_attn<<<dim3(64,16), 256, 0, stream>>>(QR, KR, VT, AO);
    // output proj + residual
    k_gemm3<2,4><<<dim3(8,32), 512, 0, stream>>>(AO, WTo, 4096, 2048, 2048, XF, (bf16*)nullptr, (const float*)nullptr);
    // FFN
    k_ln<<<4096, 256, 0, stream>>>(XF, (const float*)nullptr, (float*)nullptr, YBF, g1 + i*2048, be1 + i*2048);
    k_tr64<<<dim3(128,32), 256, 0, stream>>>(wff1 + (size_t)i*2048*8192, WT, 2048, 8192);
    k_gemm2<3,8><<<dim3(32,16), 512, 0, stream>>>(YBF, WT, 4096, 8192, 2048, (float*)nullptr, MID, bff1 + i*8192);
    k_tr64<<<dim3(32,128), 256, 0, stream>>>(wff2 + (size_t)i*8192*2048, WT, 8192, 2048);
    k_gemm3<4,4><<<dim3(8,32), 512, 0, stream>>>(MID, WT, 4096, 2048, 8192, XF, (bf16*)nullptr, bff2 + i*2048);
    // liquid gate + final LN
    k_pool<<<dim3(32,4), 256, 0, stream>>>(XF, XP);
    k_gate<<<dim3(8,4), 256, 0, stream>>>(XP, wgate + ws2, bgate + i*2048, tauff + i*2048, HF);
    k_ln<<<4096, 256, 0, stream>>>(XF, HF, XF, XBF, g2 + i*2048, be2 + i*2048);
  }

  // ---- head ----
  k_pool<<<dim3(32,4), 256, 0, stream>>>(XF, POOLED);
  k_qm<<<dim3(2,4), 256, 0, stream>>>(POOLED, w_mp, b_mp, QM);
  k_mscore<<<40, 256, 0, stream>>>(QM, bank, MATTN);
  k_msoftmax<<<4, 256, 0, stream>>>(MATTN);
  k_memmid<<<dim3(2,4,16), 256, 0, stream>>>(MATTN, bank, MPART);
  k_midsum<<<8, 256, 0, stream>>>(MPART, MIDS);
  k_feat<<<dim3(8,4), 256, 0, stream>>>(MIDS, w_mr, b_mr, POOLED, FEAT);
  k_mlp1<<<dim3(4,4), 256, 0, stream>>>(FEAT, w_a1, b_a1, A1);
  k_mlp1<<<dim3(4,4), 256, 0, stream>>>(FEAT, w_v1, b_v1, V1);
  k_out<<<4, 256, 0, stream>>>(A1, w_a2, b_a2, V1, w_v2, b_v2, out);
}

// Round 9
// 2298.254 us; speedup vs baseline: 1.0086x; 1.0086x over previous
//
#include <hip/hip_runtime.h>
#include <hip/hip_bf16.h>
#include <math.h>

typedef __hip_bfloat16 bf16;
typedef __bf16 bf16x8 __attribute__((ext_vector_type(8)));
typedef float f32x4 __attribute__((ext_vector_type(4)));

__device__ __forceinline__ f32x4 zero4() { f32x4 z; z[0]=0.f; z[1]=0.f; z[2]=0.f; z[3]=0.f; return z; }

__device__ __forceinline__ void gload_lds16(const void* g, void* l) {
  __builtin_amdgcn_global_load_lds(
      (const __attribute__((address_space(1))) void*)g,
      (__attribute__((address_space(3))) void*)l, 16, 0, 0);
}

__device__ __forceinline__ float gelu_f(float t) {
  return 0.5f*t*(1.0f+erff(t*0.70710678118654752f));
}

// 2D XCD supertile: XCD c owns a compact SW x (L/SW) rectangle of tiles.
template<int SW>
__device__ __forceinline__ void xcd_tile(int& bx, int& by) {
  const int gx = gridDim.x;
  const int nwg = gx * gridDim.y;
  const int orig = blockIdx.y * gx + blockIdx.x;
  const int L = nwg >> 3;
  const int c = orig & 7, i = orig >> 3;
  const int gxW = gx / SW;
  const int H = L / SW;
  bx = (c % gxW) * SW + i % SW;
  by = (c / gxW) * H + i / SW;
}

// ---------------- GEMM v8 "U": BM=128 x BN=256, BK=64, 8 waves, 3-slot ring, 2 phases/K-tile ----
// Counted vmcnt(6): tile T+1 issued at T-1 ph0, drained at T ph1 (~4 phases slack >= HBM latency).
// 16 MFMA + 8 ds_read_b128 per phase. LDS 144KB -> 1 block/CU.
// MODE 0: outf=acc+bias; 1: outb=acc; 2: outf+=acc; 3: outb=gelu(acc+bias); 4: outf+=acc+bias
template<int MODE, int SW>
__global__ __launch_bounds__(512, 2) void k_gemmU(
    const bf16* __restrict__ A, const bf16* __restrict__ B,
    int M, int N, int K,
    float* __restrict__ outf, bf16* __restrict__ outb,
    const float* __restrict__ bias)
{
  // slot: A 128x64 (16KB) + B 256x64 (32KB) = 48KB, x3 ring
  __shared__ __align__(16) char lds[3][49152];
  const int t = threadIdx.x;
  const int w = t>>6, l = t&63;
  const int wr = w>>2, wc = w&3;          // 2M x 4N waves; per-wave out 64x64
  const int lr = l&15, l4 = l>>4, l7 = l&7;

  int bx, by; xcd_tile<SW>(bx, by);
  const int m0 = by*128, n0 = bx*256;

  const int NT = K >> 6;
  const size_t rs = (size_t)K*2;
  const char* gA = (const char*)A + (size_t)m0*rs;
  const char* gB = (const char*)B + (size_t)n0*rs;

  // 6 gload_lds per thread per tile; LDS dest linear, global src pre-swizzled
  auto stageAll = [&](char* dst, int T){
    const size_t kb = (size_t)T*128;
    #pragma unroll
    for (int j=0;j<2;j++){
      const int row = j*64 + (t>>3);
      gload_lds16(gA + (size_t)row*rs + kb + (size_t)(((t&7)^(row&7))<<4),
                  dst + j*8192 + t*16);
    }
    #pragma unroll
    for (int j=0;j<4;j++){
      const int row = j*64 + (t>>3);
      gload_lds16(gB + (size_t)row*rs + kb + (size_t)(((t&7)^(row&7))<<4),
                  dst + 16384 + j*8192 + t*16);
    }
  };

  f32x4 acc[4][4];
  #pragma unroll
  for (int i=0;i<4;i++)
    #pragma unroll
    for (int j=0;j<4;j++) acc[i][j] = zero4();

  bf16x8 aCur[4], bCur[4];
  auto readAll = [&](const char* base, int ks){
    #pragma unroll
    for (int mi=0;mi<4;mi++){
      const int ar = wr*64 + mi*16 + lr;
      aCur[mi] = *reinterpret_cast<const bf16x8*>(base + ar*128 + (((ks*4+l4)^l7)<<4));
    }
    #pragma unroll
    for (int ni=0;ni<4;ni++){
      const int br = ni*64 + wc*16 + lr;
      bCur[ni] = *reinterpret_cast<const bf16x8*>(base + 16384 + br*128 + (((ks*4+l4)^l7)<<4));
    }
  };

  #define UMFMA                                                                     \
    __builtin_amdgcn_s_setprio(1);                                                  \
    _Pragma("unroll")                                                               \
    for (int mi=0;mi<4;mi++)                                                        \
      _Pragma("unroll")                                                             \
      for (int ni=0;ni<4;ni++)                                                      \
        acc[mi][ni] = __builtin_amdgcn_mfma_f32_16x16x32_bf16(                      \
            aCur[mi], bCur[ni], acc[mi][ni], 0,0,0);                                \
    __builtin_amdgcn_s_setprio(0);

  // prologue: stage tiles 0,1; retire tile 0 (FIFO vmcnt), publish
  stageAll(&lds[0][0], 0);
  stageAll(&lds[1][0], 1);
  asm volatile("s_waitcnt vmcnt(6)" ::: "memory");
  __builtin_amdgcn_s_barrier();

  // invariant entering T: slot[T%3]=tile T drained; slot[(T+1)%3]=tile T+1 in flight (6);
  // slot[(T+2)%3] free (last read at T-1, all waves crossed its ph1 barrier)
  for (int T=0; T<NT; ++T) {
    char* cur = &lds[T%3][0];
    char* n2  = &lds[(T+2)%3][0];
    const bool deep = (T+2 < NT);

    // ph0: ks=0 reads + stage tile T+2
    readAll(cur, 0);
    if (deep) stageAll(n2, T+2);
    asm volatile("" ::: "memory");
    __builtin_amdgcn_s_barrier();
    UMFMA;

    // ph1: ks=1 reads; counted drain retires tile T+1's 6 loads
    readAll(cur, 1);
    if (deep) { asm volatile("s_waitcnt vmcnt(6)" ::: "memory"); }
    else      { asm volatile("s_waitcnt vmcnt(0)" ::: "memory"); }
    __builtin_amdgcn_s_barrier();
    UMFMA;
  }
  #undef UMFMA

  const int rbase = m0 + wr*64 + l4*4;
  const int cb0 = n0 + wc*16 + lr;
  #pragma unroll
  for (int mi=0;mi<4;mi++)
    #pragma unroll
    for (int ni=0;ni<4;ni++) {
      const int col = cb0 + ni*64;
      #pragma unroll
      for (int q=0;q<4;q++) {
        const int row = rbase + mi*16 + q;
        const size_t idx = (size_t)row*N + col;
        float v = acc[mi][ni][q];
        if (MODE==0)      outf[idx] = v + bias[col];
        else if (MODE==1) outb[idx] = __float2bfloat16(v);
        else if (MODE==2) outf[idx] += v;
        else if (MODE==3) outb[idx] = __float2bfloat16(gelu_f(v + bias[col]));
        else if (MODE==4) outf[idx] += v + bias[col];
      }
    }
}

// ---------------- GEMM v7 (kept for N>=6144): 256x256, 4 phases, issue-all/wait-once ----------------
template<int MODE, int SW>
__global__ __launch_bounds__(512, 2) void k_gemm2(
    const bf16* __restrict__ A, const bf16* __restrict__ B,
    int M, int N, int K,
    float* __restrict__ outf, bf16* __restrict__ outb,
    const float* __restrict__ bias)
{
  __shared__ __align__(16) char lds[2][65536];
  const int t = threadIdx.x;
  const int w = t>>6, l = t&63;
  const int wr = w>>2, wc = w&3;
  const int lr = l&15, l4 = l>>4, l7 = l&7;

  int bx, by; xcd_tile<SW>(bx, by);
  const int m0 = by*256, n0 = bx*256;

  const int NT = K >> 6;
  const size_t rs = (size_t)K*2;
  const char* gA = (const char*)A + (size_t)m0*rs;
  const char* gB = (const char*)B + (size_t)n0*rs;

  auto stageU = [&](char* dstbase, const char* gbase, int T, int rowbase){
    const size_t kb = (size_t)T*128;
    #pragma unroll
    for (int i=0;i<2;i++){
      const int row = rowbase + i*64 + (t>>3);
      gload_lds16(gbase + (size_t)row*rs + kb + (size_t)(((t&7) ^ (row&7))<<4),
                  dstbase + rowbase*128 + i*8192 + t*16);
    }
  };

  f32x4 acc[2][2][4][2];
  #pragma unroll
  for (int a=0;a<2;a++)
    #pragma unroll
    for (int b=0;b<2;b++)
      #pragma unroll
      for (int c=0;c<4;c++)
        #pragma unroll
        for (int d=0;d<2;d++) acc[a][b][c][d] = zero4();

  bf16x8 aCur[4][2], bCur[2][2];
  auto readA = [&](const char* Ab, int mhalf){
    #pragma unroll
    for (int mi=0;mi<4;mi++){
      const int ar = mhalf*128 + wr*64 + mi*16 + lr;
      #pragma unroll
      for (int ks=0;ks<2;ks++)
        aCur[mi][ks] = *reinterpret_cast<const bf16x8*>(Ab + ar*128 + (((ks*4+l4) ^ l7)<<4));
    }
  };
  auto readB = [&](const char* Bb, int nhalf){
    #pragma unroll
    for (int ni=0;ni<2;ni++){
      const int br = nhalf*128 + wc*32 + ni*16 + lr;
      #pragma unroll
      for (int ks=0;ks<2;ks++)
        bCur[ni][ks] = *reinterpret_cast<const bf16x8*>(Bb + br*128 + (((ks*4+l4) ^ l7)<<4));
    }
  };

  #define QMFMA(MH,NH)                                                              \
    __builtin_amdgcn_s_setprio(1);                                                  \
    _Pragma("unroll")                                                               \
    for (int mi=0;mi<4;mi++)                                                        \
      _Pragma("unroll")                                                             \
      for (int ni=0;ni<2;ni++)                                                      \
        _Pragma("unroll")                                                           \
        for (int ks=0;ks<2;ks++)                                                    \
          acc[MH][NH][mi][ni] = __builtin_amdgcn_mfma_f32_16x16x32_bf16(            \
              aCur[mi][ks], bCur[ni][ks], acc[MH][NH][mi][ni], 0,0,0);              \
    __builtin_amdgcn_s_setprio(0);

  stageU(&lds[0][0],        gA, 0, 0);
  stageU(&lds[0][0],        gA, 0, 128);
  stageU(&lds[0][0]+32768,  gB, 0, 0);
  stageU(&lds[0][0]+32768,  gB, 0, 128);
  asm volatile("s_waitcnt vmcnt(0)" ::: "memory");
  __builtin_amdgcn_s_barrier();

  for (int T=0; T<NT; ++T) {
    const int p = T & 1;
    char* Ab = &lds[p][0];
    char* Bb = Ab + 32768;
    char* An = &lds[p^1][0];
    char* Bn = An + 32768;
    const bool more = (T+1 < NT);

    readA(Ab,0); readB(Bb,0);
    if (more) {
      stageU(An, gA, T+1, 0);
      stageU(An, gA, T+1, 128);
      stageU(Bn, gB, T+1, 0);
      stageU(Bn, gB, T+1, 128);
    }
    asm volatile("" ::: "memory");
    __builtin_amdgcn_s_barrier();
    QMFMA(0,0);

    readB(Bb,1);
    asm volatile("" ::: "memory");
    __builtin_amdgcn_s_barrier();
    QMFMA(0,1);

    readA(Ab,1);
    asm volatile("" ::: "memory");
    __builtin_amdgcn_s_barrier();
    QMFMA(1,1);

    readB(Bb,0);
    asm volatile("s_waitcnt vmcnt(0)" ::: "memory");
    __builtin_amdgcn_s_barrier();
    QMFMA(1,0);
  }
  #undef QMFMA

  const int rbase = m0 + wr*64 + l4*4;
  const int cbase = n0 + wc*32 + lr;
  #pragma unroll
  for (int mh=0;mh<2;mh++)
    #pragma unroll
    for (int nh=0;nh<2;nh++)
      #pragma unroll
      for (int mi=0;mi<4;mi++)
        #pragma unroll
        for (int ni=0;ni<2;ni++) {
          const int col = cbase + nh*128 + ni*16;
          #pragma unroll
          for (int q=0;q<4;q++) {
            const int row = rbase + mh*128 + mi*16 + q;
            const size_t idx = (size_t)row*N + col;
            float v = acc[mh][nh][mi][ni][q];
            if (MODE==0)      outf[idx] = v + bias[col];
            else if (MODE==1) outb[idx] = __float2bfloat16(v);
            else if (MODE==2) outf[idx] += v;
            else if (MODE==3) outb[idx] = __float2bfloat16(gelu_f(v + bias[col]));
            else if (MODE==4) outf[idx] += v + bias[col];
          }
        }
}

// ---------------- transpose: 64x64 tiles, float4 reads, ushort4 writes ----------------
__global__ __launch_bounds__(256) void k_tr64(const float* __restrict__ in, bf16* __restrict__ out,
                                              int K, int N)
{
  __shared__ float tile[64][65];
  const int n0 = blockIdx.x*64, k0 = blockIdx.y*64;
  const int t = threadIdx.x;
  const int tr = t>>4;
  const int tc = (t&15)*4;
  #pragma unroll
  for (int i=0;i<4;i++) {
    const int k = tr + i*16;
    float4 v = *reinterpret_cast<const float4*>(&in[(size_t)(k0+k)*N + n0 + tc]);
    tile[k][tc+0]=v.x; tile[k][tc+1]=v.y; tile[k][tc+2]=v.z; tile[k][tc+3]=v.w;
  }
  __syncthreads();
  #pragma unroll
  for (int i=0;i<4;i++) {
    const int n = tr + i*16;
    bf16 r[4];
    #pragma unroll
    for (int c=0;c<4;c++) r[c] = __float2bfloat16(tile[tc+c][n]);
    *reinterpret_cast<ushort4*>(&out[(size_t)(n0+n)*K + k0 + tc]) = *reinterpret_cast<const ushort4*>(r);
  }
}

__global__ void k_cvt(const float* __restrict__ in, bf16* __restrict__ out, int n4) {
  int i = blockIdx.x*256 + threadIdx.x;
  if (i < n4) {
    float4 v = reinterpret_cast<const float4*>(in)[i];
    out[i*4+0]=__float2bfloat16(v.x); out[i*4+1]=__float2bfloat16(v.y);
    out[i*4+2]=__float2bfloat16(v.z); out[i*4+3]=__float2bfloat16(v.w);
  }
}

__global__ void k_cossin(float* __restrict__ c, float* __restrict__ s) {
  int idx = blockIdx.x*256 + threadIdx.x;   // 1024*64
  int j = idx & 63, pos = idx >> 6;
  float inv = powf(10000.f, -(float)(2*j)/128.f);
  float a = (float)pos * inv;
  c[idx] = cosf(a); s[idx] = sinf(a);
}

// rope v2 (vectorized): lane j2 handles out dims {2*j2, 2*j2+1} of one (row,head)
__global__ void k_rope(const bf16* __restrict__ in, int instride, bf16* __restrict__ out,
                       const float* __restrict__ cosc, const float* __restrict__ sinc) {
  int idx = blockIdx.x*256 + threadIdx.x;   // 4096*16*32
  int j2 = idx & 31, h = (idx>>5) & 15, row = idx >> 9;
  int s = row & 1023;
  const bf16* rp = in + (size_t)row*instride + h*128 + j2*4;
  union { ushort4 u; bf16 b[4]; } vv;
  vv.u = *reinterpret_cast<const ushort4*>(rp);
  float a0 = __bfloat162float(vv.b[0]), b0 = __bfloat162float(vv.b[1]);
  float a1 = __bfloat162float(vv.b[2]), b1 = __bfloat162float(vv.b[3]);
  const int d = 2*j2;
  float c0 = cosc[s*64+d], s0 = sinc[s*64+d];
  float c1 = cosc[s*64+d+1], s1 = sinc[s*64+d+1];
  bf16* op = out + (size_t)row*2048 + h*128;
  union { ushort2 u; bf16 b[2]; } r0, r1;
  r0.b[0] = __float2bfloat16(a0*c0 - b0*s0);
  r0.b[1] = __float2bfloat16(a1*c1 - b1*s1);
  r1.b[0] = __float2bfloat16(a0*s0 + b0*c0);
  r1.b[1] = __float2bfloat16(a1*s1 + b1*c1);
  *reinterpret_cast<ushort2*>(op + d)      = r0.u;
  *reinterpret_cast<ushort2*>(op + 64 + d) = r1.u;
}

// V (row=b*1024+s of [4096 x instride], col=h*128+d) -> Vt[(bh*128+d)*1024 + s]
__global__ __launch_bounds__(256) void k_vtrans(const bf16* __restrict__ vlin, int instride,
                                                bf16* __restrict__ vt) {
  __shared__ bf16 tile[32][33];
  const int bh = blockIdx.x, s0 = blockIdx.y*32, d0 = blockIdx.z*32;
  const int b = bh>>4, h = bh&15;
  const int tx = threadIdx.x & 31, ty = threadIdx.x >> 5;
  #pragma unroll
  for (int i=ty;i<32;i+=8)
    tile[i][tx] = vlin[((size_t)(b*1024 + s0+i))*instride + h*128 + d0 + tx];
  __syncthreads();
  #pragma unroll
  for (int i=ty;i<32;i+=8)
    vt[((size_t)(bh*128 + d0+i))*1024 + s0 + tx] = tile[tx][i];
}

// ---------------- flash attention: LDS-staged K/V, double-buffered, XOR-swizzled ----------------
__global__ __launch_bounds__(256) void k_attn(const bf16* __restrict__ Q, const bf16* __restrict__ Kr,
                                              const bf16* __restrict__ Vt, bf16* __restrict__ O)
{
  __shared__ __align__(16) bf16 Kl[2][64*128];
  __shared__ __align__(16) bf16 Vl[2][128*64];
  __shared__ __align__(16) bf16 plds[4][16*64];
  const int t = threadIdx.x, w = t>>6, l = t&63;
  const int bh = blockIdx.x, b = bh>>4, h = bh&15;
  const int q0 = blockIdx.y*64 + w*16;
  const int l4 = l>>4, lc = l&15;

  bf16x8 qf[4];
  const bf16* qbase = Q + ((size_t)(b*1024 + q0 + lc))*2048 + h*128 + l4*8;
  #pragma unroll
  for (int kk=0;kk<4;kk++) qf[kk] = *reinterpret_cast<const bf16x8*>(qbase + kk*32);

  const char* Kg = (const char*)(Kr + ((size_t)(b*1024))*2048 + h*128);
  const char* Vg = (const char*)(Vt + ((size_t)(bh*128))*1024);

  auto stageK = [&](int buf, int kv0) {
    #pragma unroll
    for (int i=0;i<4;i++) {
      const int X = (i*256 + t)*16;
      const int row = X >> 8, colb = X & 255;
      gload_lds16(Kg + (size_t)(kv0+row)*4096 + (colb ^ ((row&7)<<4)), (char*)&Kl[buf][0] + X);
    }
  };
  auto stageV = [&](int buf, int kv0) {
    #pragma unroll
    for (int i=0;i<4;i++) {
      const int X = (i*256 + t)*16;
      const int row = X >> 7, colb = X & 127;
      gload_lds16(Vg + (size_t)row*2048 + kv0*2 + (colb ^ ((row&7)<<4)), (char*)&Vl[buf][0] + X);
    }
  };

  f32x4 oacc[8];
  #pragma unroll
  for (int n=0;n<8;n++) oacc[n]=zero4();
  float mrow[4], lrow[4];
  #pragma unroll
  for (int j=0;j<4;j++){ mrow[j]=-1e30f; lrow[j]=0.f; }
  const float scale = 0.08838834764831845f;

  stageK(0,0); stageV(0,0);
  __syncthreads();
  int cur = 0;

  for (int it=0; it<16; ++it) {
    const int kv0 = it*64;
    if (it < 15) { stageK(cur^1, kv0+64); stageV(cur^1, kv0+64); }

    f32x4 sc[4];
    #pragma unroll
    for (int c=0;c<4;c++) sc[c]=zero4();
    __builtin_amdgcn_s_setprio(1);
    #pragma unroll
    for (int c=0;c<4;c++) {
      const int krow = c*16+lc;
      const char* kp = (const char*)&Kl[cur][0] + krow*256;
      #pragma unroll
      for (int kk=0;kk<4;kk++) {
        bf16x8 kf = *reinterpret_cast<const bf16x8*>(kp + ((kk*64 + l4*16) ^ ((krow&7)<<4)));
        sc[c] = __builtin_amdgcn_mfma_f32_16x16x32_bf16(qf[kk], kf, sc[c], 0,0,0);
      }
    }
    __builtin_amdgcn_s_setprio(0);

    float alpha[4];
    #pragma unroll
    for (int j=0;j<4;j++) {
      float v0=sc[0][j]*scale, v1=sc[1][j]*scale, v2=sc[2][j]*scale, v3=sc[3][j]*scale;
      float mx = fmaxf(fmaxf(v0,v1),fmaxf(v2,v3));
      #pragma unroll
      for (int d=1;d<16;d<<=1) mx = fmaxf(mx, __shfl_xor(mx,d));
      float mn = fmaxf(mrow[j], mx);
      alpha[j] = __expf(mrow[j]-mn);
      mrow[j] = mn;
      float p0=__expf(v0-mn), p1=__expf(v1-mn), p2=__expf(v2-mn), p3=__expf(v3-mn);
      sc[0][j]=p0; sc[1][j]=p1; sc[2][j]=p2; sc[3][j]=p3;
      float ps = (p0+p1)+(p2+p3);
      #pragma unroll
      for (int d=1;d<16;d<<=1) ps += __shfl_xor(ps,d);
      lrow[j] = lrow[j]*alpha[j] + ps;
    }
    #pragma unroll
    for (int n=0;n<8;n++)
      #pragma unroll
      for (int j=0;j<4;j++) oacc[n][j]*=alpha[j];

    char* pw = (char*)&plds[w][0];
    #pragma unroll
    for (int c=0;c<4;c++)
      #pragma unroll
      for (int j=0;j<4;j++) {
        const int qrow = l4*4+j;
        *reinterpret_cast<bf16*>(pw + qrow*128 + ((c*32 + lc*2) ^ ((qrow&7)<<4))) =
            __float2bfloat16(sc[c][j]);
      }
    bf16x8 pf[2];
    #pragma unroll
    for (int ks=0;ks<2;ks++)
      pf[ks] = *reinterpret_cast<const bf16x8*>(pw + lc*128 + ((ks*64 + l4*16) ^ ((lc&7)<<4)));

    __builtin_amdgcn_s_setprio(1);
    #pragma unroll
    for (int n=0;n<8;n++) {
      const int drow = n*16+lc;
      const char* vp = (const char*)&Vl[cur][0] + drow*128;
      #pragma unroll
      for (int ks=0;ks<2;ks++) {
        bf16x8 vf = *reinterpret_cast<const bf16x8*>(vp + ((ks*64 + l4*16) ^ ((drow&7)<<4)));
        oacc[n] = __builtin_amdgcn_mfma_f32_16x16x32_bf16(pf[ks], vf, oacc[n], 0,0,0);
      }
    }
    __builtin_amdgcn_s_setprio(0);

    __syncthreads();
    cur ^= 1;
  }

  #pragma unroll
  for (int n=0;n<8;n++)
    #pragma unroll
    for (int j=0;j<4;j++) {
      float v = oacc[n][j]/lrow[j];
      O[((size_t)(b*1024 + q0 + l4*4 + j))*2048 + h*128 + n*16 + lc] = __float2bfloat16(v);
    }
}

// ---------------- LayerNorm over 2048 cols; optional per-(b,col) add; fp32+bf16 out ----------------
__global__ __launch_bounds__(256) void k_ln(const float* __restrict__ in, const float* __restrict__ addv,
                                            float* __restrict__ outf, bf16* __restrict__ outb,
                                            const float* __restrict__ g, const float* __restrict__ bta)
{
  const int row = blockIdx.x;
  const int b = row >> 10;
  const float* src = in + (size_t)row*2048;
  float vals[8];
  float s = 0.f;
  #pragma unroll
  for (int i=0;i<8;i++) {
    int c = threadIdx.x + i*256;
    float v = src[c];
    if (addv) v += addv[b*2048 + c];
    vals[i]=v; s+=v;
  }
  __shared__ float red[256];
  red[threadIdx.x]=s; __syncthreads();
  for (int o=128;o>0;o>>=1){ if(threadIdx.x<o) red[threadIdx.x]+=red[threadIdx.x+o]; __syncthreads(); }
  float mean = red[0] * (1.f/2048.f);
  __syncthreads();
  float vs=0.f;
  #pragma unroll
  for (int i=0;i<8;i++){ float d=vals[i]-mean; vs+=d*d; }
  red[threadIdx.x]=vs; __syncthreads();
  for (int o=128;o>0;o>>=1){ if(threadIdx.x<o) red[threadIdx.x]+=red[threadIdx.x+o]; __syncthreads(); }
  float inv = rsqrtf(red[0]*(1.f/2048.f) + 1e-5f);
  #pragma unroll
  for (int i=0;i<8;i++){
    int c = threadIdx.x + i*256;
    float r = (vals[i]-mean)*inv*g[c] + bta[c];
    if (outf) outf[(size_t)row*2048+c]=r;
    if (outb) outb[(size_t)row*2048+c]=__float2bfloat16(r);
  }
}

// mean over s: in (4x1024 x 2048 fp32) -> out (4 x 2048)
__global__ __launch_bounds__(256) void k_pool(const float* __restrict__ in, float* __restrict__ out) {
  const int b = blockIdx.y;
  const int c0 = blockIdx.x*64;
  const int col = threadIdx.x & 63, rg = threadIdx.x >> 6;
  float s=0.f;
  for (int i=rg*256; i<rg*256+256; ++i)
    s += in[((size_t)(b*1024) + i)*2048 + c0 + col];
  __shared__ float red[4][64];
  red[rg][col] = s; __syncthreads();
  if (threadIdx.x < 64) {
    float v = red[0][col]+red[1][col]+red[2][col]+red[3][col];
    out[b*2048 + c0 + col] = v * (1.f/1024.f);
  }
}

__global__ __launch_bounds__(256) void k_gate(const float* __restrict__ xp, const float* __restrict__ wg,
                                              const float* __restrict__ bg, const float* __restrict__ tau,
                                              float* __restrict__ hf)
{
  const int n = blockIdx.x*256 + threadIdx.x;
  const int b = blockIdx.y;
  float s = bg[n];
  const float* xr = xp + b*2048;
  for (int k=0;k<2048;k++) s += xr[k]*wg[(size_t)k*2048 + n];
  float gate = 1.f/(1.f+__expf(-s));
  float tf = 0.1f + 9.9f/(1.f+__expf(-tau[n]));
  hf[b*2048+n] = 0.1f*gate*xr[n]/tf;
}

// ---------------- head ----------------
__global__ void k_qm(const float* __restrict__ pooled, const float* __restrict__ w_mp,
                     const float* __restrict__ b_mp, float* __restrict__ qm) {
  int n = blockIdx.x*256 + threadIdx.x;  // 512
  int b = blockIdx.y;
  float s = b_mp[n];
  for (int k=0;k<2048;k++) s += pooled[b*2048+k]*w_mp[(size_t)k*512+n];
  qm[b*512+n]=s;
}

__global__ void k_mscore(const float* __restrict__ qm, const float* __restrict__ bank,
                         float* __restrict__ mattn) {
  int n = blockIdx.x*256 + threadIdx.x;
  if (n >= 10000) return;
  const float sc = 0.04419417382415922f;  // 1/sqrt(512)
  #pragma unroll
  for (int b=0;b<4;b++){
    float s=0.f;
    for (int k=0;k<512;k++) s += qm[b*512+k]*bank[(size_t)n*512+k];
    mattn[b*10000+n] = s*sc;
  }
}

__global__ __launch_bounds__(256) void k_msoftmax(float* __restrict__ mattn) {
  int b = blockIdx.x;
  __shared__ float red[256];
  float mx=-1e30f;
  for (int i=threadIdx.x;i<10000;i+=256) mx=fmaxf(mx, mattn[b*10000+i]);
  red[threadIdx.x]=mx; __syncthreads();
  for (int o=128;o>0;o>>=1){ if(threadIdx.x<o) red[threadIdx.x]=fmaxf(red[threadIdx.x],red[threadIdx.x+o]); __syncthreads(); }
  mx=red[0]; __syncthreads();
  float sm=0.f;
  for (int i=threadIdx.x;i<10000;i+=256){ float e=__expf(mattn[b*10000+i]-mx); mattn[b*10000+i]=e; sm+=e; }
  red[threadIdx.x]=sm; __syncthreads();
  for (int o=128;o>0;o>>=1){ if(threadIdx.x<o) red[threadIdx.x]+=red[threadIdx.x+o]; __syncthreads(); }
  float inv = 1.f/red[0];
  for (int i=threadIdx.x;i<10000;i+=256) mattn[b*10000+i]*=inv;
}

__global__ void k_memmid(const float* __restrict__ mattn, const float* __restrict__ bank,
                         float* __restrict__ part) {
  int d = blockIdx.x*256 + threadIdx.x;  // 512
  int b = blockIdx.y, ch = blockIdx.z;   // 16 chunks x 625
  float s=0.f;
  for (int n=ch*625;n<(ch+1)*625;n++) s += mattn[b*10000+n]*bank[(size_t)n*512+d];
  part[(size_t)ch*2048 + b*512 + d]=s;
}

__global__ void k_midsum(const float* __restrict__ part, float* __restrict__ mid) {
  int i = blockIdx.x*256 + threadIdx.x;  // 2048
  float s=0.f;
  #pragma unroll
  for (int ch=0;ch<16;ch++) s += part[(size_t)ch*2048 + i];
  mid[i]=s;
}

__global__ void k_feat(const float* __restrict__ mid, const float* __restrict__ w_mr,
                       const float* __restrict__ b_mr, const float* __restrict__ pooled,
                       float* __restrict__ feat) {
  int n = blockIdx.x*256 + threadIdx.x;  // 2048
  int b = blockIdx.y;
  float s = b_mr[n];
  for (int d=0;d<512;d++) s += mid[b*512+d]*w_mr[(size_t)d*2048+n];
  feat[b*2048+n] = pooled[b*2048+n] + s;
}

__global__ void k_mlp1(const float* __restrict__ feat, const float* __restrict__ w,
                       const float* __restrict__ bias, float* __restrict__ out) {
  int n = blockIdx.x*256 + threadIdx.x;  // 1024
  int b = blockIdx.y;
  float s = bias[n];
  for (int k=0;k<2048;k++) s += feat[b*2048+k]*w[(size_t)k*1024+n];
  out[b*1024+n] = gelu_f(s);
}

__global__ void k_out(const float* __restrict__ a1, const float* __restrict__ w_a2, const float* __restrict__ b_a2,
                      const float* __restrict__ v1, const float* __restrict__ w_v2, const float* __restrict__ b_v2,
                      float* __restrict__ out) {
  int idx = blockIdx.x*256 + threadIdx.x;  // 1024
  if (idx < 1024) {
    int b = idx>>8, n = idx&255;
    float s = b_a2[n];
    for (int k=0;k<1024;k++) s += a1[b*1024+k]*w_a2[(size_t)k*256+n];
    out[b*256+n]=s;
  }
  if (idx < 4) {
    float s = b_v2[0];
    for (int k=0;k<1024;k++) s += v1[idx*1024+k]*w_v2[k];
    out[1024+idx]=s;
  }
}

extern "C" void kernel_launch(void* const* d_in, const int* in_sizes, int n_in,
                              void* d_out, int out_size, void* d_ws, size_t ws_size,
                              hipStream_t stream)
{
  (void)in_sizes; (void)n_in; (void)out_size;
  const float* x     = (const float*)d_in[0];
  const float* w_in  = (const float*)d_in[1];
  const float* b_in  = (const float*)d_in[2];
  const float* g_in  = (const float*)d_in[3];
  const float* be_in = (const float*)d_in[4];
  const float* wq    = (const float*)d_in[5];
  const float* wk    = (const float*)d_in[6];
  const float* wv    = (const float*)d_in[7];
  const float* wo    = (const float*)d_in[8];
  const float* g1    = (const float*)d_in[11];
  const float* be1   = (const float*)d_in[12];
  const float* g2    = (const float*)d_in[13];
  const float* be2   = (const float*)d_in[14];
  const float* wff1  = (const float*)d_in[15];
  const float* bff1  = (const float*)d_in[16];
  const float* wff2  = (const float*)d_in[17];
  const float* bff2  = (const float*)d_in[18];
  const float* wgate = (const float*)d_in[19];
  const float* bgate = (const float*)d_in[20];
  const float* tauff = (const float*)d_in[21];
  const float* bank  = (const float*)d_in[22];
  const float* w_mp  = (const float*)d_in[23];
  const float* b_mp  = (const float*)d_in[24];
  const float* w_mr  = (const float*)d_in[25];
  const float* b_mr  = (const float*)d_in[26];
  const float* w_a1  = (const float*)d_in[27];
  const float* b_a1  = (const float*)d_in[28];
  const float* w_a2  = (const float*)d_in[29];
  const float* b_a2  = (const float*)d_in[30];
  const float* w_v1  = (const float*)d_in[31];
  const float* b_v1  = (const float*)d_in[32];
  const float* w_v2  = (const float*)d_in[33];
  const float* b_v2  = (const float*)d_in[34];
  float* out = (float*)d_out;

  char* ws = (char*)d_ws;
  size_t o = 0;
  auto alloc = [&](size_t bytes)->char* { char* p = ws + o; o += (bytes + 255) & ~(size_t)255; return p; };
  bf16*  WINT   = (bf16*) alloc(2048ull*1024*2);
  bf16*  WT     = (bf16*) alloc(33554432ull);
  float* XF     = (float*)alloc(33554432ull);
  bf16*  XBF    = (bf16*) alloc(16777216ull);
  float* COS    = (float*)alloc(262144);
  float* SIN    = (float*)alloc(262144);
  float* XP     = (float*)alloc(32768);
  float* HF     = (float*)alloc(32768);
  float* POOLED = (float*)alloc(32768);
  float* QM     = (float*)alloc(8192);
  float* MATTN  = (float*)alloc(160000);
  float* MPART  = (float*)alloc(131072);
  float* MIDS   = (float*)alloc(8192);
  float* FEAT   = (float*)alloc(32768);
  float* A1     = (float*)alloc(16384);
  float* V1     = (float*)alloc(16384);
  bf16*  BUF    = (bf16*) alloc(5ull*16777216);
  if (o > ws_size) return;

  const size_t EB = 8388608;
  bf16* QKV = BUF + 0*EB;          // fused q|k|v output, 4096 x 6144, spans BUF0..BUF2
  bf16* QR  = BUF + 3*EB;
  bf16* KR  = BUF + 4*EB;
  bf16* VT  = (bf16*)WT;           // 8.39M elems into dead WTq/WTk (after QKV gemm)
  bf16* AO  = BUF + 0*EB;          // reuses QKV after ropes/vtrans
  bf16* YBF = BUF + 4*EB;          // reuses KR after attention
  bf16* MID = BUF + 0*EB;          // 67MB spans BUF0..BUF3
  float* TF = (float*)(BUF + 1*EB);
  bf16* XINB = BUF + 0*EB;

  bf16* WTq = WT;            bf16* WTk = WT + 4194304;
  bf16* WTv = WT + 8388608;  bf16* WTo = WT + 12582912;

  // ---- prologue ----
  k_cossin<<<256, 256, 0, stream>>>(COS, SIN);
  k_cvt<<<4096, 256, 0, stream>>>(x, XINB, 1048576);
  k_tr64<<<dim3(32,16), 256, 0, stream>>>(w_in, WINT, 1024, 2048);
  k_gemmU<0,4><<<dim3(8,32), 512, 0, stream>>>(XINB, WINT, 4096, 2048, 1024, TF, (bf16*)nullptr, b_in);
  k_ln<<<4096, 256, 0, stream>>>(TF, (const float*)nullptr, XF, XBF, g_in, be_in);

  for (int i=0;i<2;i++) {
    const size_t ws2 = (size_t)i*2048*2048;
    k_tr64<<<dim3(32,32), 256, 0, stream>>>(wq + ws2, WTq, 2048, 2048);
    k_tr64<<<dim3(32,32), 256, 0, stream>>>(wk + ws2, WTk, 2048, 2048);
    k_tr64<<<dim3(32,32), 256, 0, stream>>>(wv + ws2, WTv, 2048, 2048);
    k_tr64<<<dim3(32,32), 256, 0, stream>>>(wo + ws2, WTo, 2048, 2048);
    // fused QKV projection: N=6144 (grid 24x16, XCD chunk 6x8)
    k_gemm2<1,6><<<dim3(24,16), 512, 0, stream>>>(XBF, WTq, 4096, 6144, 2048, (float*)nullptr, QKV, (const float*)nullptr);
    // RoPE + V transpose (VT lives in dead WTq/WTk region)
    k_rope<<<8192, 256, 0, stream>>>(QKV,        6144, QR, COS, SIN);
    k_rope<<<8192, 256, 0, stream>>>(QKV + 2048, 6144, KR, COS, SIN);
    k_vtrans<<<dim3(64,32,4), 256, 0, stream>>>(QKV + 4096, 6144, VT);
    // attention
    k_attn<<<dim3(64,16), 256, 0, stream>>>(QR, KR, VT, AO);
    // output proj + residual
    k_gemmU<2,4><<<dim3(8,32), 512, 0, stream>>>(AO, WTo, 4096, 2048, 2048, XF, (bf16*)nullptr, (const float*)nullptr);
    // FFN
    k_ln<<<4096, 256, 0, stream>>>(XF, (const float*)nullptr, (float*)nullptr, YBF, g1 + i*2048, be1 + i*2048);
    k_tr64<<<dim3(128,32), 256, 0, stream>>>(wff1 + (size_t)i*2048*8192, WT, 2048, 8192);
    k_gemm2<3,8><<<dim3(32,16), 512, 0, stream>>>(YBF, WT, 4096, 8192, 2048, (float*)nullptr, MID, bff1 + i*8192);
    k_tr64<<<dim3(32,128), 256, 0, stream>>>(wff2 + (size_t)i*8192*2048, WT, 8192, 2048);
    k_gemmU<4,4><<<dim3(8,32), 512, 0, stream>>>(MID, WT, 4096, 2048, 8192, XF, (bf16*)nullptr, bff2 + i*2048);
    // liquid gate + final LN
    k_pool<<<dim3(32,4), 256, 0, stream>>>(XF, XP);
    k_gate<<<dim3(8,4), 256, 0, stream>>>(XP, wgate + ws2, bgate + i*2048, tauff + i*2048, HF);
    k_ln<<<4096, 256, 0, stream>>>(XF, HF, XF, XBF, g2 + i*2048, be2 + i*2048);
  }

  // ---- head ----
  k_pool<<<dim3(32,4), 256, 0, stream>>>(XF, POOLED);
  k_qm<<<dim3(2,4), 256, 0, stream>>>(POOLED, w_mp, b_mp, QM);
  k_mscore<<<40, 256, 0, stream>>>(QM, bank, MATTN);
  k_msoftmax<<<4, 256, 0, stream>>>(MATTN);
  k_memmid<<<dim3(2,4,16), 256, 0, stream>>>(MATTN, bank, MPART);
  k_midsum<<<8, 256, 0, stream>>>(MPART, MIDS);
  k_feat<<<dim3(8,4), 256, 0, stream>>>(MIDS, w_mr, b_mr, POOLED, FEAT);
  k_mlp1<<<dim3(4,4), 256, 0, stream>>>(FEAT, w_a1, b_a1, A1);
  k_mlp1<<<dim3(4,4), 256, 0, stream>>>(FEAT, w_v1, b_v1, V1);
  k_out<<<4, 256, 0, stream>>>(A1, w_a2, b_a2, V1, w_v2, b_v2, out);
}